// Round 5
// baseline (92.326 us; speedup 1.0000x reference)
//
#include <hip/hip_runtime.h>
#include <hip/hip_bf16.h>

typedef __attribute__((ext_vector_type(8))) short bf16x8;
typedef __attribute__((ext_vector_type(4))) short s16x4;
typedef __attribute__((ext_vector_type(4))) float f32x4;

__device__ __forceinline__ short f2bf(float f) {
    __hip_bfloat16 h = __float2bfloat16(f);
    short s;
    __builtin_memcpy(&s, &h, 2);
    return s;
}

__device__ __forceinline__ float lrelu(float v) {
    return fmaxf(v, 0.05f * v);   // slope in (0,1)
}

#define MFMA(a, b, c) __builtin_amdgcn_mfma_f32_16x16x32_bf16((a), (b), (c), 0, 0, 0)

// ---------------------------------------------------------------------------
// Kernel 1: per-row MLP into XCD-sliced layout.
// catT[b][row][16] bf16, b = feature-block 0..7 (features 16b..16b+15).
// Slice b is contiguous (R*32 B = 3.2 MB) so one XCD's L2 can hold it.
// Row 0 = pad -> MLP(0) = 0. Swapped-operand MFMA as before; stores per
// (tile,block) are 512 B fully contiguous across the wave.
// ---------------------------------------------------------------------------
__global__ __launch_bounds__(256, 3) void mlp_rows_kernel(
    const float* __restrict__ z,
    const float* __restrict__ w1,
    const float* __restrict__ w2,
    short* __restrict__ catT,
    int rows_p1)
{
    __shared__ __align__(16) short wlds[12288];   // 16 w1 frags + 8 w2 frags

    const int tid = threadIdx.x;
    const int lane = tid & 63;
    const int g = lane >> 4;
    const int u = lane & 15;

    // one-time: w1,w2 fp32 -> bf16 fragments in LDS (frag f, lane l @ f*1024+l*16)
    #pragma unroll
    for (int j = 0; j < 12; ++j) {
        const int c = tid + (j << 8);
        const float* src;
        int row, col, fbase;
        if (c < 2048) {            // w1: 64x128
            row = c >> 5; col = (c & 31) << 2;
            src = w1 + row * 128 + col;
            fbase = ((row >> 4) << 2) + (col >> 5);
        } else {                   // w2: 64x64
            const int c2 = c - 2048;
            row = c2 >> 4; col = (c2 & 15) << 2;
            src = w2 + row * 64 + col;
            fbase = 16 + ((row >> 4) << 1) + (col >> 5);
        }
        const int rem = col & 31;
        const int gg = (rem >> 2) & 3;
        const int eh = rem >> 4;
        float4 v = *reinterpret_cast<const float4*>(src);
        s16x4 p;
        p[0] = f2bf(v.x); p[1] = f2bf(v.y); p[2] = f2bf(v.z); p[3] = f2bf(v.w);
        const int idx = ((fbase << 6) + (gg << 4) + (row & 15)) * 8 + (eh << 2);
        *reinterpret_cast<s16x4*>(&wlds[idx]) = p;
    }
    __syncthreads();

    const bf16x8* __restrict__ wv = reinterpret_cast<const bf16x8*>(wlds);

    const int waves_per_blk = blockDim.x >> 6;
    const int wave = blockIdx.x * waves_per_blk + (tid >> 6);
    const int nwaves = gridDim.x * waves_per_blk;
    const int nchunks = (rows_p1 + 31) >> 5;
    const size_t R16 = (size_t)rows_p1 * 16;   // shorts per slice

    for (int c = wave; c < nchunks; c += nwaves) {
        const int base = c << 5;
        const int r0 = base + u;         // tile-0 table row for this lane
        const int r1 = base + 16 + u;    // tile-1 table row

        bf16x8 bx[2][4];
        #pragma unroll
        for (int t = 0; t < 2; ++t) {
            const int r = t ? r1 : r0;
            const bool valid = (r >= 1) && (r < rows_p1);
            const float* srcp = z + (size_t)(r - 1) * 128 + 4 * g;
            #pragma unroll
            for (int s = 0; s < 4; ++s) {
                float4 lo = make_float4(0.f, 0.f, 0.f, 0.f);
                float4 hi = make_float4(0.f, 0.f, 0.f, 0.f);
                if (valid) {
                    lo = *reinterpret_cast<const float4*>(srcp + 32 * s);
                    hi = *reinterpret_cast<const float4*>(srcp + 32 * s + 16);
                }
                bf16x8 f;
                f[0] = f2bf(lo.x); f[1] = f2bf(lo.y); f[2] = f2bf(lo.z); f[3] = f2bf(lo.w);
                f[4] = f2bf(hi.x); f[5] = f2bf(hi.y); f[6] = f2bf(hi.z); f[7] = f2bf(hi.w);
                bx[t][s] = f;
            }
        }

        const bool st0 = r0 < rows_p1;
        const bool st1 = r1 < rows_p1;
        // slice-local store bases: catT[(b*R + r)*16 + 4g]
        short* c0 = catT + (size_t)r0 * 16 + 4 * g;
        short* c1 = catT + (size_t)r1 * 16 + 4 * g;

        f32x4 d2[4][2];
        #pragma unroll
        for (int b2 = 0; b2 < 4; ++b2) {
            d2[b2][0] = (f32x4){0.f, 0.f, 0.f, 0.f};
            d2[b2][1] = (f32x4){0.f, 0.f, 0.f, 0.f};
        }

        #pragma unroll
        for (int s2 = 0; s2 < 2; ++s2) {
            bf16x8 p2[2];
            #pragma unroll
            for (int h = 0; h < 2; ++h) {
                const int b = 2 * s2 + h;
                f32x4 d1[2];
                d1[0] = (f32x4){0.f, 0.f, 0.f, 0.f};
                d1[1] = (f32x4){0.f, 0.f, 0.f, 0.f};
                #pragma unroll
                for (int s = 0; s < 4; ++s) {
                    const bf16x8 wf = wv[((b << 2) + s) * 64 + lane];
                    d1[0] = MFMA(wf, bx[0][s], d1[0]);
                    d1[1] = MFMA(wf, bx[1][s], d1[1]);
                }
                #pragma unroll
                for (int t = 0; t < 2; ++t) {
                    s16x4 pk;
                    #pragma unroll
                    for (int q = 0; q < 4; ++q) {
                        const short bv = f2bf(lrelu(d1[t][q]));
                        p2[t][4 * h + q] = bv;
                        pk[q] = bv;
                    }
                    // h1 features 16b+4g+q -> slice b
                    if (t == 0 ? st0 : st1)
                        *reinterpret_cast<s16x4*>((t ? c1 : c0) + (size_t)b * R16) = pk;
                }
            }
            #pragma unroll
            for (int b2 = 0; b2 < 4; ++b2) {
                const bf16x8 wf = wv[1024 + ((b2 << 1) + s2) * 64 + lane];
                d2[b2][0] = MFMA(wf, p2[0], d2[b2][0]);
                d2[b2][1] = MFMA(wf, p2[1], d2[b2][1]);
            }
        }

        #pragma unroll
        for (int b2 = 0; b2 < 4; ++b2) {
            #pragma unroll
            for (int t = 0; t < 2; ++t) {
                s16x4 pk;
                #pragma unroll
                for (int q = 0; q < 4; ++q)
                    pk[q] = f2bf(lrelu(d2[b2][t][q]));
                // h2 features 64+16b2+4g+q -> slice 4+b2
                if (t == 0 ? st0 : st1)
                    *reinterpret_cast<s16x4*>((t ? c1 : c0) + (size_t)(4 + b2) * R16) = pk;
            }
        }
    }
}

// ---------------------------------------------------------------------------
// Kernel 2: XCD-sharded gather + max. Block i serves feature-slice b = i&7,
// so (with round-robin blockIdx->XCD dispatch) each XCD's L2 only holds its
// own 3.2 MB slice -> gather re-reads become L2 hits.
// Wave layout: lane = (nsub = l>>3) n-sub-row, (f2 = l&7) uint feature-pair.
// Per task: 8 n's, 32 positions in registers, no cross-lane ops for the max.
// idx double-buffered with named A/B buffers (static indexing).
// ---------------------------------------------------------------------------
__device__ __forceinline__ void gx_load_idx(const int* __restrict__ neigh,
                                            int task, int nsub, int n_rows,
                                            int (&ix)[32])
{
    int nn = task * 8 + nsub;
    if (nn >= n_rows) nn = n_rows - 1;   // safe clamp; store is guarded
    const int4* np = reinterpret_cast<const int4*>(neigh + (size_t)nn * 32);
    #pragma unroll
    for (int j = 0; j < 8; ++j) {
        int4 v = np[j];
        ix[4 * j + 0] = v.x; ix[4 * j + 1] = v.y;
        ix[4 * j + 2] = v.z; ix[4 * j + 3] = v.w;
    }
}

__device__ __forceinline__ void gx_gather(const unsigned int* __restrict__ slice,
                                          const int (&ix)[32], int f2,
                                          unsigned (&d)[32])
{
    #pragma unroll
    for (int p = 0; p < 32; ++p)
        d[p] = slice[(size_t)(unsigned)ix[p] * 8u + (unsigned)f2];
}

__device__ __forceinline__ void gx_reduce_store(const unsigned (&d)[32],
                                                float* __restrict__ out,
                                                int task, int nsub, int f2,
                                                int b, int n_rows)
{
    float m0 = __uint_as_float(d[0] << 16);
    float m1 = __uint_as_float(d[0] & 0xffff0000u);
    #pragma unroll
    for (int p = 1; p < 32; ++p) {
        m0 = fmaxf(m0, __uint_as_float(d[p] << 16));
        m1 = fmaxf(m1, __uint_as_float(d[p] & 0xffff0000u));
    }
    const int nn = task * 8 + nsub;
    if (nn < n_rows)
        *reinterpret_cast<float2*>(out + (size_t)nn * 128 + 16 * b + 2 * f2) =
            make_float2(m0, m1);
}

__global__ __launch_bounds__(256) void gather_max_xcd_kernel(
    const unsigned int* __restrict__ catU,   // [8][R][8] uints (2 bf16 each)
    const int* __restrict__ neigh,
    float* __restrict__ out,
    int n_rows, int R)
{
    const int tid = threadIdx.x;
    const int lane = tid & 63;
    const int f2 = lane & 7;
    const int nsub = lane >> 3;
    const int b = blockIdx.x & 7;                  // feature slice == XCD hint
    const int wpb = blockDim.x >> 6;
    int t = (blockIdx.x >> 3) * wpb + (tid >> 6);
    const int wstride = (gridDim.x >> 3) * wpb;
    const int ntasks = (n_rows + 7) >> 3;
    const unsigned int* slice = catU + (size_t)b * (size_t)R * 8;

    if (t >= ntasks) return;

    int idxA[32], idxB[32];
    unsigned d[32];

    gx_load_idx(neigh, t, nsub, n_rows, idxA);

    while (true) {
        // process A, prefetch into B
        gx_gather(slice, idxA, f2, d);
        {
            const int t2 = t + wstride;
            if (t2 < ntasks) gx_load_idx(neigh, t2, nsub, n_rows, idxB);
        }
        gx_reduce_store(d, out, t, nsub, f2, b, n_rows);
        t += wstride;
        if (t >= ntasks) break;

        // process B, prefetch into A
        gx_gather(slice, idxB, f2, d);
        {
            const int t2 = t + wstride;
            if (t2 < ntasks) gx_load_idx(neigh, t2, nsub, n_rows, idxA);
        }
        gx_reduce_store(d, out, t, nsub, f2, b, n_rows);
        t += wstride;
        if (t >= ntasks) break;
    }
}

// ---------------------------------------------------------------------------
// Fallback (ws too small): proven fused fp32-gather kernel (R2 semantics).
// ---------------------------------------------------------------------------
struct WaveCtx {
    const bf16x8* wv;
    const int* neigh;
    float* out;
    int lane, g, u, n_rows;
};

__device__ __forceinline__ void compute_n(const WaveCtx& cx, bf16x8 (&bx)[2][4], int n)
{
    f32x4 d2[4][2];
    #pragma unroll
    for (int b2 = 0; b2 < 4; ++b2) {
        d2[b2][0] = (f32x4){0.f, 0.f, 0.f, 0.f};
        d2[b2][1] = (f32x4){0.f, 0.f, 0.f, 0.f};
    }
    float V1[16], V2[16];

    #pragma unroll
    for (int s2 = 0; s2 < 2; ++s2) {
        bf16x8 p2[2];
        #pragma unroll
        for (int h = 0; h < 2; ++h) {
            const int b = 2 * s2 + h;
            f32x4 d1[2];
            d1[0] = (f32x4){0.f, 0.f, 0.f, 0.f};
            d1[1] = (f32x4){0.f, 0.f, 0.f, 0.f};
            #pragma unroll
            for (int s = 0; s < 4; ++s) {
                const bf16x8 wf = cx.wv[((b << 2) + s) * 64 + cx.lane];
                d1[0] = MFMA(wf, bx[0][s], d1[0]);
                d1[1] = MFMA(wf, bx[1][s], d1[1]);
            }
            #pragma unroll
            for (int t = 0; t < 2; ++t) {
                #pragma unroll
                for (int q = 0; q < 4; ++q) {
                    float v = lrelu(d1[t][q]);
                    d1[t][q] = v;
                    p2[t][4 * h + q] = f2bf(v);
                }
            }
            #pragma unroll
            for (int q = 0; q < 4; ++q)
                V1[b * 4 + q] = fmaxf(d1[0][q], d1[1][q]);
        }
        #pragma unroll
        for (int b2 = 0; b2 < 4; ++b2) {
            const bf16x8 wf = cx.wv[1024 + ((b2 << 1) + s2) * 64 + cx.lane];
            d2[b2][0] = MFMA(wf, p2[0], d2[b2][0]);
            d2[b2][1] = MFMA(wf, p2[1], d2[b2][1]);
        }
    }

    #pragma unroll
    for (int b2 = 0; b2 < 4; ++b2) {
        #pragma unroll
        for (int q = 0; q < 4; ++q)
            V2[b2 * 4 + q] = lrelu(fmaxf(d2[b2][0][q], d2[b2][1][q]));
    }

    const int u = cx.u;
    #pragma unroll
    for (int k = 0; k < 4; ++k) {
        const int m = 1 << k;
        const bool hi = (u & m) != 0;
        #pragma unroll
        for (int j = 0; j < (8 >> k); ++j) {
            float k1 = hi ? V1[2 * j + 1] : V1[2 * j];
            float s1 = hi ? V1[2 * j] : V1[2 * j + 1];
            float k2 = hi ? V2[2 * j + 1] : V2[2 * j];
            float s2v = hi ? V2[2 * j] : V2[2 * j + 1];
            V1[j] = fmaxf(k1, __shfl_xor(s1, m, 64));
            V2[j] = fmaxf(k2, __shfl_xor(s2v, m, 64));
        }
    }

    const int l = cx.lane;
    const int src = 16 * ((l >> 2) & 3) + ((l >> 4) << 2) + (l & 3);
    float v1 = __shfl(V1[0], src, 64);
    float v2 = __shfl(V2[0], src, 64);
    float* op = cx.out + (size_t)n * 128;
    op[l] = v1;
    op[64 + l] = v2;
}

__global__ __launch_bounds__(256, 3) void neigh_enco_fp32_kernel(
    const float* __restrict__ z,
    const int* __restrict__ neigh,
    const float* __restrict__ w1,
    const float* __restrict__ w2,
    float* __restrict__ out,
    int n_rows, int z_rows)
{
    __shared__ __align__(16) short wlds[12288];
    const int tid = threadIdx.x;
    const int lane = tid & 63;
    const int g = lane >> 4;
    const int u = lane & 15;

    #pragma unroll
    for (int j = 0; j < 12; ++j) {
        const int c = tid + (j << 8);
        const float* src;
        int row, col, fbase;
        if (c < 2048) {
            row = c >> 5; col = (c & 31) << 2;
            src = w1 + row * 128 + col;
            fbase = ((row >> 4) << 2) + (col >> 5);
        } else {
            const int c2 = c - 2048;
            row = c2 >> 4; col = (c2 & 15) << 2;
            src = w2 + row * 64 + col;
            fbase = 16 + ((row >> 4) << 1) + (col >> 5);
        }
        const int rem = col & 31;
        const int gg = (rem >> 2) & 3;
        const int eh = rem >> 4;
        float4 v = *reinterpret_cast<const float4*>(src);
        s16x4 p;
        p[0] = f2bf(v.x); p[1] = f2bf(v.y); p[2] = f2bf(v.z); p[3] = f2bf(v.w);
        const int idx = ((fbase << 6) + (gg << 4) + (row & 15)) * 8 + (eh << 2);
        *reinterpret_cast<s16x4*>(&wlds[idx]) = p;
    }
    __syncthreads();

    WaveCtx cx;
    cx.wv = reinterpret_cast<const bf16x8*>(wlds);
    cx.neigh = neigh; cx.out = out;
    cx.lane = lane; cx.g = g; cx.u = u; cx.n_rows = n_rows;

    const int waves_per_blk = blockDim.x >> 6;
    const int wave = blockIdx.x * waves_per_blk + (tid >> 6);
    const int nwaves = gridDim.x * waves_per_blk;
    const unsigned zu = (unsigned)z_rows;

    for (int n = wave; n < n_rows; n += nwaves) {
        unsigned r0 = (unsigned)neigh[n * 32 + u] - 1u;
        unsigned r1 = (unsigned)neigh[n * 32 + 16 + u] - 1u;
        bf16x8 bx[2][4];
        #pragma unroll
        for (int t = 0; t < 2; ++t) {
            const unsigned r = t ? r1 : r0;
            const bool valid = r < zu;
            const float* base = z + (size_t)r * 128 + 4 * g;
            #pragma unroll
            for (int s = 0; s < 4; ++s) {
                float4 lo = make_float4(0.f, 0.f, 0.f, 0.f);
                float4 hi = make_float4(0.f, 0.f, 0.f, 0.f);
                if (valid) {
                    lo = *reinterpret_cast<const float4*>(base + 32 * s);
                    hi = *reinterpret_cast<const float4*>(base + 32 * s + 16);
                }
                bf16x8 f;
                f[0] = f2bf(lo.x); f[1] = f2bf(lo.y); f[2] = f2bf(lo.z); f[3] = f2bf(lo.w);
                f[4] = f2bf(hi.x); f[5] = f2bf(hi.y); f[6] = f2bf(hi.z); f[7] = f2bf(hi.w);
                bx[t][s] = f;
            }
        }
        compute_n(cx, bx, n);
    }
}

extern "C" void kernel_launch(void* const* d_in, const int* in_sizes, int n_in,
                              void* d_out, int out_size, void* d_ws, size_t ws_size,
                              hipStream_t stream) {
    const float* z     = (const float*)d_in[0];
    const int*   neigh = (const int*)d_in[1];
    const float* w1    = (const float*)d_in[2];
    const float* w2    = (const float*)d_in[3];
    float* out = (float*)d_out;
    const int z_rows = in_sizes[0] / 128;
    const int n_rows = in_sizes[1] / 32;
    const int rows_p1 = z_rows + 1;

    const size_t cat_bytes = (size_t)rows_p1 * 128 * sizeof(short);
    if (ws_size >= cat_bytes) {
        short* catT = (short*)d_ws;
        const int nchunks = (rows_p1 + 31) / 32;
        hipLaunchKernelGGL(mlp_rows_kernel, dim3((nchunks + 3) / 4), dim3(256),
                           0, stream, z, w1, w2, catT, rows_p1);
        hipLaunchKernelGGL(gather_max_xcd_kernel, dim3(2048), dim3(256), 0, stream,
                           (const unsigned int*)catT, neigh, out, n_rows, rows_p1);
    } else {
        hipLaunchKernelGGL(neigh_enco_fp32_kernel, dim3(2048), dim3(256), 0, stream,
                           z, neigh, w1, w2, out, n_rows, z_rows);
    }
}